// Round 2
// baseline (715.655 us; speedup 1.0000x reference)
//
#include <hip/hip_runtime.h>

// Problem: B=32, N=36, D=2048, C=4, H=512.  K = 2H = 1024 stacked (coord|feat).
// Out[b,i,d] = max_j sum_k  Wcat[k,d] * (crfr[b,j,k] * clfl[b,i,k])  + mm[b,i,d]
//   k<512 :  cl*cr*W_cout ;  k>=512 : fl*fr*W_fout

typedef __attribute__((ext_vector_type(8))) short short8;
typedef __attribute__((ext_vector_type(4))) float f32x4;

__device__ __forceinline__ float bf2f(unsigned short h) {
  return __uint_as_float(((unsigned int)h) << 16);
}
__device__ __forceinline__ unsigned short f2bf(float f) {
  unsigned int u = __float_as_uint(f);
  u += 0x7FFFu + ((u >> 16) & 1u);
  return (unsigned short)(u >> 16);
}

// ---------------------------------------------------------------------------
// K1: cl = coords @ W_cl -> Lw[:, 0:512], cr = coords @ W_cr -> Rw[:, 0:512]
__global__ __launch_bounds__(256) void k_proj_coords(
    const float* __restrict__ coords, const float* __restrict__ Wcl,
    const float* __restrict__ Wcr, unsigned short* __restrict__ Lw,
    unsigned short* __restrict__ Rw) {
  int idx = blockIdx.x * 256 + threadIdx.x;  // 0 .. 1152*512-1
  int row = idx >> 9, h = idx & 511;
  const float* c = coords + row * 4;
  float a0 = c[0], a1 = c[1], a2 = c[2], a3 = c[3];
  float vl = a0 * Wcl[h] + a1 * Wcl[512 + h] + a2 * Wcl[1024 + h] + a3 * Wcl[1536 + h];
  float vr = a0 * Wcr[h] + a1 * Wcr[512 + h] + a2 * Wcr[1024 + h] + a3 * Wcr[1536 + h];
  Lw[(size_t)row * 1024 + h] = f2bf(vl);
  Rw[(size_t)row * 1024 + h] = f2bf(vr);
}

// ---------------------------------------------------------------------------
// K2: build bf16 transposed weights.
//  WT[d][k]    (2048 x 1024): k<512 -> W_cout[k][d], else W_fout[k-512][d]
//  WlrT[c][dd] (1024 x 2048): c<512 -> W_fl[dd][c],  else W_fr[dd][c-512]
__global__ __launch_bounds__(256) void k_conv_w(
    const float* __restrict__ Wcout, const float* __restrict__ Wfout,
    const float* __restrict__ Wfl, const float* __restrict__ Wfr,
    unsigned short* __restrict__ WT, unsigned short* __restrict__ WlrT) {
  int idx = blockIdx.x * 256 + threadIdx.x;
  if (idx < 2048 * 1024) {
    int d = idx >> 10, k = idx & 1023;
    float v = (k < 512) ? Wcout[(size_t)k * 2048 + d]
                        : Wfout[(size_t)(k - 512) * 2048 + d];
    WT[idx] = f2bf(v);
  } else {
    int j = idx - 2048 * 1024;
    int c = j >> 11, dd = j & 2047;
    float v = (c < 512) ? Wfl[(size_t)dd * 512 + c]
                        : Wfr[(size_t)dd * 512 + c - 512];
    WlrT[j] = f2bf(v);
  }
}

// ---------------------------------------------------------------------------
// K3: feature projection  O[row, col] = sum_d mm[row,d] * Wlr[d,col]
//  col<512 -> fl -> Lw[row][512+col] ; col>=512 -> fr -> Rw[row][col]
__global__ __launch_bounds__(64) void k_proj_feat(
    const float* __restrict__ mm, const unsigned short* __restrict__ WlrT,
    unsigned short* __restrict__ Lw, unsigned short* __restrict__ Rw) {
  const int lane = threadIdx.x;
  const int n = lane & 15, q = lane >> 4;
  const int m0 = blockIdx.x * 32;
  const int c0 = blockIdx.y * 64;

  f32x4 zero = {0.f, 0.f, 0.f, 0.f};
  f32x4 acc[2][4];
#pragma unroll
  for (int r = 0; r < 2; ++r)
#pragma unroll
    for (int c = 0; c < 4; ++c) acc[r][c] = zero;

#pragma unroll 2
  for (int k = 0; k < 2048; k += 32) {
    short8 a[2], b[4];
#pragma unroll
    for (int r = 0; r < 2; ++r) {
      const float* src = mm + (size_t)(m0 + r * 16 + n) * 2048 + k + q * 8;
      float4 x = *(const float4*)src;
      float4 y = *(const float4*)(src + 4);
      short8 t;
      t[0] = (short)f2bf(x.x); t[1] = (short)f2bf(x.y);
      t[2] = (short)f2bf(x.z); t[3] = (short)f2bf(x.w);
      t[4] = (short)f2bf(y.x); t[5] = (short)f2bf(y.y);
      t[6] = (short)f2bf(y.z); t[7] = (short)f2bf(y.w);
      a[r] = t;
    }
#pragma unroll
    for (int c = 0; c < 4; ++c)
      b[c] = *(const short8*)(WlrT + (size_t)(c0 + c * 16 + n) * 2048 + k + q * 8);
#pragma unroll
    for (int r = 0; r < 2; ++r)
#pragma unroll
      for (int c = 0; c < 4; ++c)
        acc[r][c] = __builtin_amdgcn_mfma_f32_16x16x32_bf16(a[r], b[c], acc[r][c], 0, 0, 0);
  }

#pragma unroll
  for (int r = 0; r < 2; ++r)
#pragma unroll
    for (int c = 0; c < 4; ++c)
#pragma unroll
      for (int e = 0; e < 4; ++e) {
        int row = m0 + r * 16 + q * 4 + e;
        int col = c0 + c * 16 + n;
        unsigned short v = f2bf(acc[r][c][e]);
        if (col < 512) Lw[(size_t)row * 1024 + 512 + col] = v;
        else           Rw[(size_t)row * 1024 + col] = v;
      }
}

// ---------------------------------------------------------------------------
// K4: fused pairwise GEMM + max-over-j + residual.
// Per block: one (b,i) group g, one 256-wide d-tile dt.
//   C[d, j] = sum_k WT[d,k] * (crfr[b,j,k] * clfl[b,i,k]),  j padded 36->48
//   Out[g, d] = max_{j<36} C[d,j] + mm[g,d]
// A (WT) read straight from global (L2-resident); B (products) staged in LDS,
// row stride 72 bf16 (=36 dwords) so each 8-lane b128 phase is conflict-free.
__global__ __launch_bounds__(256) void k_pairwise(
    const unsigned short* __restrict__ Lw, const unsigned short* __restrict__ Rw,
    const unsigned short* __restrict__ WT, const float* __restrict__ mm,
    float* __restrict__ out) {
  __shared__ __align__(16) unsigned short lP[48 * 72];
  __shared__ __align__(16) unsigned short clfl[1024];

  const int tid = threadIdx.x;
  const int bx = blockIdx.x;
  const int dt = bx / 1152;       // 0..7  (same-dt blocks contiguous: W-slice L2 reuse)
  const int g  = bx % 1152;       // (b,i) group
  const int lane = tid & 63;
  const int w = tid >> 6;
  const int n = lane & 15;
  const int q = lane >> 4;
  const int dbase = dt * 256 + w * 64;

  // init: load clfl row (1024 bf16 = 256 x uint2), zero j-pad rows of lP
  ((uint2*)clfl)[tid] = ((const uint2*)(Lw + (size_t)g * 1024))[tid];
  for (int z = tid; z < 12 * 72; z += 256) lP[36 * 72 + z] = 0;

  f32x4 zero = {0.f, 0.f, 0.f, 0.f};
  f32x4 acc[4][3];
#pragma unroll
  for (int r = 0; r < 4; ++r)
#pragma unroll
    for (int c = 0; c < 3; ++c) acc[r][c] = zero;

  // j runs over rows of the SAME batch: base row = g - (g % 36)
  const unsigned short* crfrB = Rw + (size_t)(g - (g % 36)) * 1024;

  for (int ch = 0; ch < 16; ++ch) {
    const int k0 = ch * 64;
    __syncthreads();  // prior-chunk MFMA done (first iter: init visible)
    // stage products lP[j][0:64] for j<36 : 36*8 = 288 b128 tasks
#pragma unroll
    for (int it = 0; it < 2; ++it) {
      int task = tid + it * 256;
      if (task < 288) {
        int j = task >> 3, seg = task & 7;
        short8 cr8 = *(const short8*)(crfrB + (size_t)j * 1024 + k0 + seg * 8);
        short8 cf8 = *(const short8*)(clfl + k0 + seg * 8);
        short8 p;
#pragma unroll
        for (int e = 0; e < 8; ++e)
          p[e] = (short)f2bf(bf2f((unsigned short)cr8[e]) *
                             bf2f((unsigned short)cf8[e]));
        *(short8*)(lP + j * 72 + seg * 8) = p;
      }
    }
    __syncthreads();
#pragma unroll
    for (int kk = 0; kk < 2; ++kk) {
      const int kb = k0 + kk * 32 + q * 8;
      short8 a[4], bb[3];
#pragma unroll
      for (int r = 0; r < 4; ++r)
        a[r] = *(const short8*)(WT + (size_t)(dbase + r * 16 + n) * 1024 + kb);
#pragma unroll
      for (int c = 0; c < 3; ++c)
        bb[c] = *(const short8*)(lP + (c * 16 + n) * 72 + kk * 32 + q * 8);
#pragma unroll
      for (int r = 0; r < 4; ++r)
#pragma unroll
        for (int c = 0; c < 3; ++c)
          acc[r][c] = __builtin_amdgcn_mfma_f32_16x16x32_bf16(a[r], bb[c], acc[r][c], 0, 0, 0);
    }
  }

  // epilogue: masked max over j (cols), then residual add.
  // C/D layout: col = lane&15 (j within tile), row(d) = q*4 + e
#pragma unroll
  for (int r = 0; r < 4; ++r) {
#pragma unroll
    for (int e = 0; e < 4; ++e) {
      float v = fmaxf(acc[r][0][e], acc[r][1][e]);      // j in [0,32)
      float v2 = (n < 4) ? acc[r][2][e] : -1e30f;       // j in [32,36)
      v = fmaxf(v, v2);
#pragma unroll
      for (int s = 1; s < 16; s <<= 1) v = fmaxf(v, __shfl_xor(v, s, 64));
      if (n == 0) {
        int d = dbase + r * 16 + q * 4 + e;
        size_t o = (size_t)g * 2048 + d;
        out[o] = v + mm[o];
      }
    }
  }
}

// ---------------------------------------------------------------------------
extern "C" void kernel_launch(void* const* d_in, const int* in_sizes, int n_in,
                              void* d_out, int out_size, void* d_ws, size_t ws_size,
                              hipStream_t stream) {
  const float* mm     = (const float*)d_in[0];
  const float* coords = (const float*)d_in[1];
  const float* Wcl    = (const float*)d_in[2];
  const float* Wcr    = (const float*)d_in[3];
  const float* Wcout  = (const float*)d_in[4];
  const float* Wfl    = (const float*)d_in[5];
  const float* Wfr    = (const float*)d_in[6];
  const float* Wfout  = (const float*)d_in[7];
  float* out = (float*)d_out;

  // workspace layout (bf16), ~12.6 MB total
  unsigned short* Lw   = (unsigned short*)d_ws;   // [1152][1024]  cl | fl
  unsigned short* Rw   = Lw + 1152 * 1024;        // [1152][1024]  cr | fr
  unsigned short* WT   = Rw + 1152 * 1024;        // [2048][1024]  Wcat^T
  unsigned short* WlrT = WT + 2048 * 1024;        // [1024][2048]  (Wfl|Wfr)^T

  k_proj_coords<<<2304, 256, 0, stream>>>(coords, Wcl, Wcr, Lw, Rw);
  k_conv_w<<<16384, 256, 0, stream>>>(Wcout, Wfout, Wfl, Wfr, WT, WlrT);
  k_proj_feat<<<dim3(36, 16), 64, 0, stream>>>(mm, WlrT, Lw, Rw);
  k_pairwise<<<8 * 1152, 256, 0, stream>>>(Lw, Rw, WT, mm, out);
}

// Round 3
// 644.698 us; speedup vs baseline: 1.1101x; 1.1101x over previous
//
#include <hip/hip_runtime.h>

// B=32, N=36, D=2048, C=4, H=512.  K = 2H = 1024 stacked (coord|feat).
// Out[b,i,d] = max_j sum_k Wcat[k,d] * (crfr[b,j,k] * clfl[b,i,k]) + mm[b,i,d]

typedef __attribute__((ext_vector_type(8))) short short8;
typedef __attribute__((ext_vector_type(4))) float f32x4;

__device__ __forceinline__ float bf2f(unsigned short h) {
  return __uint_as_float(((unsigned int)h) << 16);
}
__device__ __forceinline__ unsigned short f2bf(float f) {
  unsigned int u = __float_as_uint(f);
  u += 0x7FFFu + ((u >> 16) & 1u);
  return (unsigned short)(u >> 16);
}

// ---------------------------------------------------------------------------
// K1: cl = coords @ W_cl -> Lw[:,0:512], cr = coords @ W_cr -> Rw[:,0:512]
__global__ __launch_bounds__(256) void k_proj_coords(
    const float* __restrict__ coords, const float* __restrict__ Wcl,
    const float* __restrict__ Wcr, unsigned short* __restrict__ Lw,
    unsigned short* __restrict__ Rw) {
  int idx = blockIdx.x * 256 + threadIdx.x;  // 0 .. 1152*512-1
  int row = idx >> 9, h = idx & 511;
  const float* c = coords + row * 4;
  float a0 = c[0], a1 = c[1], a2 = c[2], a3 = c[3];
  float vl = a0 * Wcl[h] + a1 * Wcl[512 + h] + a2 * Wcl[1024 + h] + a3 * Wcl[1536 + h];
  float vr = a0 * Wcr[h] + a1 * Wcr[512 + h] + a2 * Wcr[1024 + h] + a3 * Wcr[1536 + h];
  Lw[(size_t)row * 1024 + h] = f2bf(vl);
  Rw[(size_t)row * 1024 + h] = f2bf(vr);
}

// ---------------------------------------------------------------------------
// K2: build bf16 weights in MFMA *fragment order* (coalesced reads in K3/K4).
// WS  granule gi  = ((g2*32+kc)*4+q)*16+n ; elem e: d=g2*16+n, k=kc*32+q*8+e
//     src: k<512 ? W_cout[k][d] : W_fout[k-512][d]          (262144 granules)
// WS2 granule gj  = ((cg*64+kc)*4+q)*16+n ; elem e: col=cg*16+n, dd=kc*32+q*8+e
//     src: col<512 ? W_fl[dd][col] : W_fr[dd][col-512]      (262144 granules)
__global__ __launch_bounds__(256) void k_conv_w(
    const float* __restrict__ Wcout, const float* __restrict__ Wfout,
    const float* __restrict__ Wfl, const float* __restrict__ Wfr,
    unsigned short* __restrict__ WS, unsigned short* __restrict__ WS2) {
  int gi = blockIdx.x * 256 + threadIdx.x;  // 0..524287
  if (gi < 262144) {
    int n = gi & 15, qv = (gi >> 4) & 3, kc = (gi >> 6) & 31, g2 = gi >> 11;
    int d = g2 * 16 + n;
    int kbase = kc * 32 + qv * 8;
    const float* src = (kbase < 512) ? (Wcout + (size_t)kbase * 2048 + d)
                                     : (Wfout + (size_t)(kbase - 512) * 2048 + d);
    short8 o;
#pragma unroll
    for (int e = 0; e < 8; ++e) o[e] = (short)f2bf(src[(size_t)e * 2048]);
    *(short8*)(WS + (size_t)gi * 8) = o;
  } else {
    int gj = gi - 262144;
    int n = gj & 15, qv = (gj >> 4) & 3, kc = (gj >> 6) & 63, cg = gj >> 12;
    int col = cg * 16 + n;
    int dbase = kc * 32 + qv * 8;
    const float* src = (col < 512) ? (Wfl + (size_t)dbase * 512 + col)
                                   : (Wfr + (size_t)dbase * 512 + (col - 512));
    short8 o;
#pragma unroll
    for (int e = 0; e < 8; ++e) o[e] = (short)f2bf(src[(size_t)e * 512]);
    *(short8*)(WS2 + (size_t)gj * 8) = o;
  }
}

// ---------------------------------------------------------------------------
// K3: feature projection O[row,col] = sum_dd mm[row,dd]*Wlr[dd,col]
//  col<512 -> fl -> Lw[row][512+col] ; else fr -> Rw[row][col]
// 4 waves/block; wave tile 16 rows x 16 cols; B reads wave-contiguous from WS2.
__global__ __launch_bounds__(256) void k_proj_feat(
    const float* __restrict__ mm, const unsigned short* __restrict__ WS2,
    unsigned short* __restrict__ Lw, unsigned short* __restrict__ Rw) {
  const int tid = threadIdx.x;
  const int lane = tid & 63, w = tid >> 6;
  const int n = lane & 15, q = lane >> 4;
  const int m0 = blockIdx.y * 16;
  const int cg = blockIdx.x * 4 + w;  // 0..63
  const int c0 = cg * 16;

  f32x4 acc = {0.f, 0.f, 0.f, 0.f};
#pragma unroll 4
  for (int kc = 0; kc < 64; ++kc) {
    const float* src = mm + (size_t)(m0 + n) * 2048 + kc * 32 + q * 8;
    float4 x = *(const float4*)src;
    float4 y = *(const float4*)(src + 4);
    short8 a;
    a[0] = (short)f2bf(x.x); a[1] = (short)f2bf(x.y);
    a[2] = (short)f2bf(x.z); a[3] = (short)f2bf(x.w);
    a[4] = (short)f2bf(y.x); a[5] = (short)f2bf(y.y);
    a[6] = (short)f2bf(y.z); a[7] = (short)f2bf(y.w);
    short8 b = *(const short8*)(WS2 + (size_t)(cg * 64 + kc) * 512 + lane * 8);
    acc = __builtin_amdgcn_mfma_f32_16x16x32_bf16(a, b, acc, 0, 0, 0);
  }
#pragma unroll
  for (int e = 0; e < 4; ++e) {
    int row = m0 + q * 4 + e;
    int col = c0 + n;
    unsigned short v = f2bf(acc[e]);
    if (col < 512) Lw[(size_t)row * 1024 + 512 + col] = v;
    else           Rw[(size_t)row * 1024 + col] = v;
  }
}

// ---------------------------------------------------------------------------
// K4: fused pairwise GEMM + max-over-j + residual. 2 i's per block (shared A).
// grid 4608 = 8 dt x 32 b x 18 p ; block d-width 256, wave d-width 64.
// lP fragment-order, XOR-swizzled (slot ^= kk*4+qq): conflict-free wr/rd.
// Double-buffered, 1 barrier/chunk; staging split load->mfma->finish.
__global__ __launch_bounds__(256) void k_pairwise(
    const unsigned short* __restrict__ Lw, const unsigned short* __restrict__ Rw,
    const unsigned short* __restrict__ WS, const float* __restrict__ mm,
    float* __restrict__ out) {
  __shared__ __align__(16) unsigned short lP[2][2][3072];  // [ii][buf][slot*8]
  __shared__ __align__(16) float clf[2][1024];

  const int tid = threadIdx.x;
  const int lane = tid & 63, w = tid >> 6;
  const int n = lane & 15, q = lane >> 4;
  const int bx = blockIdx.x;
  const int dt = bx / 576;
  const int r2 = bx % 576;
  const int b = r2 / 18, p = r2 % 18;
  const int g0 = b * 36 + p * 2;

  // zero all lP (pad slots c=2,n>=4 stay zero forever)
  {
    uint4 z4 = {0u, 0u, 0u, 0u};
    uint4* z = (uint4*)&lP[0][0][0];
#pragma unroll
    for (int t = 0; t < 6; ++t) z[tid + t * 256] = z4;
  }
  // clf: rows g0, g0+1 of Lw (full 1024-k cl|fl vector) -> fp32
#pragma unroll
  for (int t0 = 0; t0 < 8; ++t0) {
    int t = tid + t0 * 256;
    int ii = t >> 10, k = t & 1023;
    clf[ii][k] = bf2f(Lw[(size_t)(g0 + ii) * 1024 + k]);
  }

  const unsigned short* crfrB = Rw + (size_t)b * 36 * 1024;

  f32x4 acc[2][4][3];
#pragma unroll
  for (int ii = 0; ii < 2; ++ii)
#pragma unroll
    for (int r = 0; r < 4; ++r)
#pragma unroll
      for (int c = 0; c < 3; ++c) acc[ii][r][c] = (f32x4){0.f, 0.f, 0.f, 0.f};

  // staging task A: t=tid (always, t<288 since tid<256); task B: t=tid+256 (tid<32)
  const int jA = tid >> 3, segA = tid & 7;
  const int tB = tid + 256;
  const int jB = tB >> 3, segB = tB & 7;
  const bool hasB = (tid < 32);
  const int offA = ((((segA >> 2) * 3 + (jA >> 4)) * 64 + (segA & 3) * 16 + (jA & 15)) ^
                    ((segA >> 2) * 4 + (segA & 3))) * 8;
  const int offB = ((((segB >> 2) * 3 + (jB >> 4)) * 64 + (segB & 3) * 16 + (jB & 15)) ^
                    ((segB >> 2) * 4 + (segB & 3))) * 8;

  short8 crA, crB;
#define SLOAD(k0)                                                             \
  do {                                                                        \
    crA = *(const short8*)(crfrB + (size_t)jA * 1024 + (k0) + segA * 8);      \
    if (hasB) crB = *(const short8*)(crfrB + (size_t)jB * 1024 + (k0) + segB * 8); \
  } while (0)

#define SFIN(k0, buf)                                                         \
  do {                                                                        \
    {                                                                         \
      const float* c0p = &clf[0][(k0) + segA * 8];                            \
      const float* c1p = &clf[1][(k0) + segA * 8];                            \
      short8 p0, p1;                                                          \
      _Pragma("unroll") for (int e = 0; e < 8; ++e) {                         \
        float cr = bf2f((unsigned short)crA[e]);                              \
        p0[e] = (short)f2bf(cr * c0p[e]);                                     \
        p1[e] = (short)f2bf(cr * c1p[e]);                                     \
      }                                                                       \
      *(short8*)(&lP[0][buf][offA]) = p0;                                     \
      *(short8*)(&lP[1][buf][offA]) = p1;                                     \
    }                                                                         \
    if (hasB) {                                                               \
      const float* c0p = &clf[0][(k0) + segB * 8];                            \
      const float* c1p = &clf[1][(k0) + segB * 8];                            \
      short8 p0, p1;                                                          \
      _Pragma("unroll") for (int e = 0; e < 8; ++e) {                         \
        float cr = bf2f((unsigned short)crB[e]);                              \
        p0[e] = (short)f2bf(cr * c0p[e]);                                     \
        p1[e] = (short)f2bf(cr * c1p[e]);                                     \
      }                                                                       \
      *(short8*)(&lP[0][buf][offB]) = p0;                                     \
      *(short8*)(&lP[1][buf][offB]) = p1;                                     \
    }                                                                         \
  } while (0)

  SLOAD(0);
  __syncthreads();  // clf + lP zeros visible
  SFIN(0, 0);
  __syncthreads();

#pragma unroll 2
  for (int ch = 0; ch < 16; ++ch) {
    const int buf = ch & 1, nbuf = buf ^ 1;
    if (ch < 15) SLOAD((ch + 1) * 64);
    // MFMA on current buffer
#pragma unroll
    for (int kk = 0; kk < 2; ++kk) {
      short8 bb[2][3];
#pragma unroll
      for (int c = 0; c < 3; ++c) {
        int g = (((kk * 3 + c) * 64 + lane) ^ (kk * 4 + q)) * 8;
        bb[0][c] = *(const short8*)(&lP[0][buf][g]);
        bb[1][c] = *(const short8*)(&lP[1][buf][g]);
      }
#pragma unroll
      for (int r = 0; r < 4; ++r) {
        int dgrp = dt * 16 + w * 4 + r;
        short8 a = *(const short8*)(WS + (size_t)((dgrp * 32 + ch * 2 + kk) * 64 + lane) * 8);
#pragma unroll
        for (int c = 0; c < 3; ++c) {
          acc[0][r][c] = __builtin_amdgcn_mfma_f32_16x16x32_bf16(a, bb[0][c], acc[0][r][c], 0, 0, 0);
          acc[1][r][c] = __builtin_amdgcn_mfma_f32_16x16x32_bf16(a, bb[1][c], acc[1][r][c], 0, 0, 0);
        }
      }
    }
    if (ch < 15) SFIN((ch + 1) * 64, nbuf);
    __syncthreads();
  }

  // epilogue: masked max over j-columns, shuffle-reduce over n, residual add.
#pragma unroll
  for (int ii = 0; ii < 2; ++ii) {
#pragma unroll
    for (int r = 0; r < 4; ++r) {
#pragma unroll
      for (int e = 0; e < 4; ++e) {
        float v = fmaxf(acc[ii][r][0][e], acc[ii][r][1][e]);  // j in [0,32)
        float v2 = (n < 4) ? acc[ii][r][2][e] : -1e30f;       // j in [32,36)
        v = fmaxf(v, v2);
#pragma unroll
        for (int s = 1; s < 16; s <<= 1) v = fmaxf(v, __shfl_xor(v, s, 64));
        if (n == 0) {
          int d = dt * 256 + w * 64 + r * 16 + q * 4 + e;
          size_t o = (size_t)(g0 + ii) * 2048 + d;
          out[o] = v + mm[o];
        }
      }
    }
  }
#undef SLOAD
#undef SFIN
}

// ---------------------------------------------------------------------------
extern "C" void kernel_launch(void* const* d_in, const int* in_sizes, int n_in,
                              void* d_out, int out_size, void* d_ws, size_t ws_size,
                              hipStream_t stream) {
  const float* mm     = (const float*)d_in[0];
  const float* coords = (const float*)d_in[1];
  const float* Wcl    = (const float*)d_in[2];
  const float* Wcr    = (const float*)d_in[3];
  const float* Wcout  = (const float*)d_in[4];
  const float* Wfl    = (const float*)d_in[5];
  const float* Wfr    = (const float*)d_in[6];
  const float* Wfout  = (const float*)d_in[7];
  float* out = (float*)d_out;

  // workspace (bf16), ~12.6 MB
  unsigned short* Lw  = (unsigned short*)d_ws;    // [1152][1024]  cl | fl
  unsigned short* Rw  = Lw + 1152 * 1024;         // [1152][1024]  cr | fr
  unsigned short* WS  = Rw + 1152 * 1024;         // 262144 granules x 8 (Wcat^T swizzled)
  unsigned short* WS2 = WS + 262144 * 8;          // 262144 granules x 8 ((Wfl|Wfr)^T swizzled)

  k_proj_coords<<<2304, 256, 0, stream>>>(coords, Wcl, Wcr, Lw, Rw);
  k_conv_w<<<2048, 256, 0, stream>>>(Wcout, Wfout, Wfl, Wfr, WS, WS2);
  k_proj_feat<<<dim3(16, 72), 256, 0, stream>>>(mm, WS2, Lw, Rw);
  k_pairwise<<<4608, 256, 0, stream>>>(Lw, Rw, WS, mm, out);
}

// Round 4
// 371.346 us; speedup vs baseline: 1.9272x; 1.7361x over previous
//
#include <hip/hip_runtime.h>

// B=32, N=36, D=2048, C=4, H=512.  K = 2H = 1024 stacked (coord|feat).
// Out[b,i,d] = max_j sum_k Wcat[k,d] * (crfr[b,j,k] * clfl[b,i,k]) + mm[b,i,d]

typedef __attribute__((ext_vector_type(8))) short short8;
typedef __attribute__((ext_vector_type(4))) short short4v;
typedef __attribute__((ext_vector_type(4))) float f32x4;

__device__ __forceinline__ float bf2f(unsigned short h) {
  return __uint_as_float(((unsigned int)h) << 16);
}
__device__ __forceinline__ unsigned short f2bf(float f) {
  unsigned int u = __float_as_uint(f);
  u += 0x7FFFu + ((u >> 16) & 1u);
  return (unsigned short)(u >> 16);
}

// ---------------------------------------------------------------------------
// K12: fused prep.
//  bid < 2304 : coords proj  (cl -> Lw[:,0:512], cr -> Rw[:,0:512])
//               + mm fp32->bf16 (mmb, 4 elems/thread)
//  bid >= 2304: weights -> MFMA fragment order (WS for K4, WS2 for K3)
__global__ __launch_bounds__(256) void k_prep(
    const float* __restrict__ coords, const float* __restrict__ Wcl,
    const float* __restrict__ Wcr, const float* __restrict__ mm,
    const float* __restrict__ Wcout, const float* __restrict__ Wfout,
    const float* __restrict__ Wfl, const float* __restrict__ Wfr,
    unsigned short* __restrict__ Lw, unsigned short* __restrict__ Rw,
    unsigned short* __restrict__ mmb, unsigned short* __restrict__ WS,
    unsigned short* __restrict__ WS2) {
  const int bid = blockIdx.x;
  if (bid < 2304) {
    int idx = bid * 256 + threadIdx.x;  // 0 .. 1152*512-1
    int row = idx >> 9, h = idx & 511;
    const float* c = coords + row * 4;
    float a0 = c[0], a1 = c[1], a2 = c[2], a3 = c[3];
    float vl = a0 * Wcl[h] + a1 * Wcl[512 + h] + a2 * Wcl[1024 + h] + a3 * Wcl[1536 + h];
    float vr = a0 * Wcr[h] + a1 * Wcr[512 + h] + a2 * Wcr[1024 + h] + a3 * Wcr[1536 + h];
    Lw[(size_t)row * 1024 + h] = f2bf(vl);
    Rw[(size_t)row * 1024 + h] = f2bf(vr);
    float4 m4 = *(const float4*)(mm + (size_t)row * 2048 + h * 4);
    short4v o;
    o[0] = (short)f2bf(m4.x); o[1] = (short)f2bf(m4.y);
    o[2] = (short)f2bf(m4.z); o[3] = (short)f2bf(m4.w);
    *(short4v*)(mmb + (size_t)row * 2048 + h * 4) = o;
  } else {
    int gi = (bid - 2304) * 256 + threadIdx.x;  // 0..524287
    if (gi < 262144) {
      // WS granule gi = ((g2*32+kc)*4+q)*16+n ; elem e: d=g2*16+n, k=kc*32+q*8+e
      int n = gi & 15, qv = (gi >> 4) & 3, kc = (gi >> 6) & 31, g2 = gi >> 11;
      int d = g2 * 16 + n;
      int kbase = kc * 32 + qv * 8;
      const float* src = (kbase < 512) ? (Wcout + (size_t)kbase * 2048 + d)
                                       : (Wfout + (size_t)(kbase - 512) * 2048 + d);
      short8 o;
#pragma unroll
      for (int e = 0; e < 8; ++e) o[e] = (short)f2bf(src[(size_t)e * 2048]);
      *(short8*)(WS + (size_t)gi * 8) = o;
    } else {
      // WS2 granule gj = ((cg*64+kc)*4+q)*16+n ; elem e: col=cg*16+n, dd=kc*32+q*8+e
      int gj = gi - 262144;
      int n = gj & 15, qv = (gj >> 4) & 3, kc = (gj >> 6) & 63, cg = gj >> 12;
      int col = cg * 16 + n;
      int dbase = kc * 32 + qv * 8;
      const float* src = (col < 512) ? (Wfl + (size_t)dbase * 512 + col)
                                     : (Wfr + (size_t)dbase * 512 + (col - 512));
      short8 o;
#pragma unroll
      for (int e = 0; e < 8; ++e) o[e] = (short)f2bf(src[(size_t)e * 512]);
      *(short8*)(WS2 + (size_t)gj * 8) = o;
    }
  }
}

// ---------------------------------------------------------------------------
// K3: feature projection O[row,col] = sum_dd mmb[row,dd]*Wlr[dd,col]
//  col<512 -> fl -> Lw[row][512+col] ; else fr -> Rw[row][col]
// 4 waves/block; wave tile 16 rows x 16 cols; A bf16 direct, B from WS2.
__global__ __launch_bounds__(256) void k_proj_feat(
    const unsigned short* __restrict__ mmb, const unsigned short* __restrict__ WS2,
    unsigned short* __restrict__ Lw, unsigned short* __restrict__ Rw) {
  const int tid = threadIdx.x;
  const int lane = tid & 63, w = tid >> 6;
  const int n = lane & 15, q = lane >> 4;
  const int m0 = blockIdx.y * 16;
  const int cg = blockIdx.x * 4 + w;  // 0..63
  const int c0 = cg * 16;

  f32x4 acc = {0.f, 0.f, 0.f, 0.f};
#pragma unroll 4
  for (int kc = 0; kc < 64; ++kc) {
    short8 a = *(const short8*)(mmb + (size_t)(m0 + n) * 2048 + kc * 32 + q * 8);
    short8 b = *(const short8*)(WS2 + (size_t)(cg * 64 + kc) * 512 + lane * 8);
    acc = __builtin_amdgcn_mfma_f32_16x16x32_bf16(a, b, acc, 0, 0, 0);
  }
#pragma unroll
  for (int e = 0; e < 4; ++e) {
    int row = m0 + q * 4 + e;
    int col = c0 + n;
    unsigned short v = f2bf(acc[e]);
    if (col < 512) Lw[(size_t)row * 1024 + 512 + col] = v;
    else           Rw[(size_t)row * 1024 + col] = v;
  }
}

// ---------------------------------------------------------------------------
// K4: fused pairwise GEMM + max-over-j + residual. 2 i's per block (shared A).
// grid 4608 = 8 dt x 32 b x 18 p ; block d-width 256, wave d-width 64.
// lP fragment-order, XOR-swizzled: conflict-free wr/rd (verified r3: conflicts=0).
// __launch_bounds__(256,2): cap unified VGPR+AGPR <=256 -> 2 waves/SIMD.
// A-fragments register-double-buffered (load ch+1 during ch's MFMA section).
__global__ __launch_bounds__(256, 2) void k_pairwise(
    const unsigned short* __restrict__ Lw, const unsigned short* __restrict__ Rw,
    const unsigned short* __restrict__ WS, const float* __restrict__ mm,
    float* __restrict__ out) {
  __shared__ __align__(16) unsigned short lP[2][2][3072];  // [ii][buf][slot*8]
  __shared__ __align__(16) float clf[2][1024];

  const int tid = threadIdx.x;
  const int lane = tid & 63, w = tid >> 6;
  const int n = lane & 15, q = lane >> 4;
  const int bx = blockIdx.x;
  const int dt = bx / 576;
  const int r2 = bx % 576;
  const int b = r2 / 18, p = r2 % 18;
  const int g0 = b * 36 + p * 2;

  // zero all lP (pad slots stay zero forever)
  {
    uint4 z4 = {0u, 0u, 0u, 0u};
    uint4* z = (uint4*)&lP[0][0][0];
#pragma unroll
    for (int t = 0; t < 6; ++t) z[tid + t * 256] = z4;
  }
  // clf: rows g0, g0+1 of Lw (full 1024-k cl|fl vector) -> fp32
#pragma unroll
  for (int t0 = 0; t0 < 8; ++t0) {
    int t = tid + t0 * 256;
    int ii = t >> 10, k = t & 1023;
    clf[ii][k] = bf2f(Lw[(size_t)(g0 + ii) * 1024 + k]);
  }

  const unsigned short* crfrB = Rw + (size_t)b * 36 * 1024;

  f32x4 acc[2][4][3];
#pragma unroll
  for (int ii = 0; ii < 2; ++ii)
#pragma unroll
    for (int r = 0; r < 4; ++r)
#pragma unroll
      for (int c = 0; c < 3; ++c) acc[ii][r][c] = (f32x4){0.f, 0.f, 0.f, 0.f};

  // staging task A: t=tid (<288 always); task B: t=tid+256 (tid<32)
  const int jA = tid >> 3, segA = tid & 7;
  const int tB = tid + 256;
  const int jB = tB >> 3, segB = tB & 7;
  const bool hasB = (tid < 32);
  const int offA = ((((segA >> 2) * 3 + (jA >> 4)) * 64 + (segA & 3) * 16 + (jA & 15)) ^
                    ((segA >> 2) * 4 + (segA & 3))) * 8;
  const int offB = ((((segB >> 2) * 3 + (jB >> 4)) * 64 + (segB & 3) * 16 + (jB & 15)) ^
                    ((segB >> 2) * 4 + (segB & 3))) * 8;

  short8 crA, crB;
#define SLOAD(k0)                                                             \
  do {                                                                        \
    crA = *(const short8*)(crfrB + (size_t)jA * 1024 + (k0) + segA * 8);      \
    if (hasB) crB = *(const short8*)(crfrB + (size_t)jB * 1024 + (k0) + segB * 8); \
  } while (0)

#define SFIN(k0, buf)                                                         \
  do {                                                                        \
    {                                                                         \
      const float* c0p = &clf[0][(k0) + segA * 8];                            \
      const float* c1p = &clf[1][(k0) + segA * 8];                            \
      short8 p0, p1;                                                          \
      _Pragma("unroll") for (int e = 0; e < 8; ++e) {                         \
        float cr = bf2f((unsigned short)crA[e]);                              \
        p0[e] = (short)f2bf(cr * c0p[e]);                                     \
        p1[e] = (short)f2bf(cr * c1p[e]);                                     \
      }                                                                       \
      *(short8*)(&lP[0][buf][offA]) = p0;                                     \
      *(short8*)(&lP[1][buf][offA]) = p1;                                     \
    }                                                                         \
    if (hasB) {                                                               \
      const float* c0p = &clf[0][(k0) + segB * 8];                            \
      const float* c1p = &clf[1][(k0) + segB * 8];                            \
      short8 p0, p1;                                                          \
      _Pragma("unroll") for (int e = 0; e < 8; ++e) {                         \
        float cr = bf2f((unsigned short)crB[e]);                              \
        p0[e] = (short)f2bf(cr * c0p[e]);                                     \
        p1[e] = (short)f2bf(cr * c1p[e]);                                     \
      }                                                                       \
      *(short8*)(&lP[0][buf][offB]) = p0;                                     \
      *(short8*)(&lP[1][buf][offB]) = p1;                                     \
    }                                                                         \
  } while (0)

  // A-fragment address: granule ((dgrp*32 + ch*2 + kk)*64 + lane), dgrp=dt*16+w*4+r
#define APTR(ch, kk, r) \
  (const short8*)(WS + (size_t)((((dt * 16 + w * 4 + (r)) * 32 + (ch) * 2 + (kk)) * 64 + lane)) * 8)

  short8 aR[2][4], aN[2][4];
#pragma unroll
  for (int kk = 0; kk < 2; ++kk)
#pragma unroll
    for (int r = 0; r < 4; ++r) aR[kk][r] = *APTR(0, kk, r);

  SLOAD(0);
  __syncthreads();  // clf + lP zeros visible
  SFIN(0, 0);
  __syncthreads();

#pragma unroll 2
  for (int ch = 0; ch < 16; ++ch) {
    const int buf = ch & 1, nbuf = buf ^ 1;
    if (ch < 15) {
      SLOAD((ch + 1) * 64);
#pragma unroll
      for (int kk = 0; kk < 2; ++kk)
#pragma unroll
        for (int r = 0; r < 4; ++r) aN[kk][r] = *APTR(ch + 1, kk, r);
    }
    // MFMA on current buffer, prefetched A-frags
#pragma unroll
    for (int kk = 0; kk < 2; ++kk) {
      short8 bb[2][3];
#pragma unroll
      for (int c = 0; c < 3; ++c) {
        int g = (((kk * 3 + c) * 64 + lane) ^ (kk * 4 + q)) * 8;
        bb[0][c] = *(const short8*)(&lP[0][buf][g]);
        bb[1][c] = *(const short8*)(&lP[1][buf][g]);
      }
#pragma unroll
      for (int r = 0; r < 4; ++r) {
#pragma unroll
        for (int c = 0; c < 3; ++c) {
          acc[0][r][c] = __builtin_amdgcn_mfma_f32_16x16x32_bf16(aR[kk][r], bb[0][c], acc[0][r][c], 0, 0, 0);
          acc[1][r][c] = __builtin_amdgcn_mfma_f32_16x16x32_bf16(aR[kk][r], bb[1][c], acc[1][r][c], 0, 0, 0);
        }
      }
    }
    if (ch < 15) SFIN((ch + 1) * 64, nbuf);
    __syncthreads();
#pragma unroll
    for (int kk = 0; kk < 2; ++kk)
#pragma unroll
      for (int r = 0; r < 4; ++r) aR[kk][r] = aN[kk][r];
  }

  // epilogue: masked max over j-columns, shuffle-reduce over n, residual add.
#pragma unroll
  for (int ii = 0; ii < 2; ++ii) {
#pragma unroll
    for (int r = 0; r < 4; ++r) {
#pragma unroll
      for (int e = 0; e < 4; ++e) {
        float v = fmaxf(acc[ii][r][0][e], acc[ii][r][1][e]);  // j in [0,32)
        float v2 = (n < 4) ? acc[ii][r][2][e] : -1e30f;       // j in [32,36)
        v = fmaxf(v, v2);
#pragma unroll
        for (int s = 1; s < 16; s <<= 1) v = fmaxf(v, __shfl_xor(v, s, 64));
        if (n == 0) {
          int d = dt * 256 + w * 64 + r * 16 + q * 4 + e;
          size_t o = (size_t)(g0 + ii) * 2048 + d;
          out[o] = v + mm[o];
        }
      }
    }
  }
#undef SLOAD
#undef SFIN
#undef APTR
}

// ---------------------------------------------------------------------------
extern "C" void kernel_launch(void* const* d_in, const int* in_sizes, int n_in,
                              void* d_out, int out_size, void* d_ws, size_t ws_size,
                              hipStream_t stream) {
  const float* mm     = (const float*)d_in[0];
  const float* coords = (const float*)d_in[1];
  const float* Wcl    = (const float*)d_in[2];
  const float* Wcr    = (const float*)d_in[3];
  const float* Wcout  = (const float*)d_in[4];
  const float* Wfl    = (const float*)d_in[5];
  const float* Wfr    = (const float*)d_in[6];
  const float* Wfout  = (const float*)d_in[7];
  float* out = (float*)d_out;

  // workspace (bf16), ~17.3 MB
  unsigned short* Lw  = (unsigned short*)d_ws;    // [1152][1024]  cl | fl
  unsigned short* Rw  = Lw + 1152 * 1024;         // [1152][1024]  cr | fr
  unsigned short* WS  = Rw + 1152 * 1024;         // 262144 granules x 8 (Wcat^T swizzled)
  unsigned short* WS2 = WS + 262144 * 8;          // 262144 granules x 8 ((Wfl|Wfr)^T swizzled)
  unsigned short* mmb = WS2 + 262144 * 8;         // [1152][2048]  mm in bf16

  k_prep<<<2304 + 2048, 256, 0, stream>>>(coords, Wcl, Wcr, mm, Wcout, Wfout,
                                          Wfl, Wfr, Lw, Rw, mmb, WS, WS2);
  k_proj_feat<<<dim3(16, 72), 256, 0, stream>>>(mmb, WS2, Lw, Rw);
  k_pairwise<<<4608, 256, 0, stream>>>(Lw, Rw, WS, mm, out);
}

// Round 5
// 338.666 us; speedup vs baseline: 2.1132x; 1.0965x over previous
//
#include <hip/hip_runtime.h>

// B=32, N=36, D=2048, C=4, H=512.  K = 2H = 1024 stacked (coord|feat).
// Out[b,i,d] = max_j sum_k Wcat[k,d] * (crfr[b,j,k] * clfl[b,i,k]) + mm[b,i,d]

typedef __attribute__((ext_vector_type(8))) short short8;
typedef __attribute__((ext_vector_type(4))) short short4v;
typedef __attribute__((ext_vector_type(4))) float f32x4;

__device__ __forceinline__ float bf2f(unsigned short h) {
  return __uint_as_float(((unsigned int)h) << 16);
}
__device__ __forceinline__ unsigned short f2bf(float f) {
  unsigned int u = __float_as_uint(f);
  u += 0x7FFFu + ((u >> 16) & 1u);
  return (unsigned short)(u >> 16);
}
// async global->LDS, 16B per lane; lds dest is wave-uniform base + lane*16
__device__ __forceinline__ void gl2lds16(const void* g, void* l) {
  __builtin_amdgcn_global_load_lds(
      (const __attribute__((address_space(1))) unsigned int*)g,
      (__attribute__((address_space(3))) unsigned int*)l, 16, 0, 0);
}

// ---------------------------------------------------------------------------
// K_prep: bid<2304: coords proj (cl->Lw[:,0:512], cr->Rw[:,0:512]) + mm->bf16.
//         bid>=2304: weights -> MFMA fragment order (WS for K4, WS2 for K3).
__global__ __launch_bounds__(256) void k_prep(
    const float* __restrict__ coords, const float* __restrict__ Wcl,
    const float* __restrict__ Wcr, const float* __restrict__ mm,
    const float* __restrict__ Wcout, const float* __restrict__ Wfout,
    const float* __restrict__ Wfl, const float* __restrict__ Wfr,
    unsigned short* __restrict__ Lw, unsigned short* __restrict__ Rw,
    unsigned short* __restrict__ mmb, unsigned short* __restrict__ WS,
    unsigned short* __restrict__ WS2) {
  const int bid = blockIdx.x;
  if (bid < 2304) {
    int idx = bid * 256 + threadIdx.x;  // 0 .. 1152*512-1
    int row = idx >> 9, h = idx & 511;
    const float* c = coords + row * 4;
    float a0 = c[0], a1 = c[1], a2 = c[2], a3 = c[3];
    float vl = a0 * Wcl[h] + a1 * Wcl[512 + h] + a2 * Wcl[1024 + h] + a3 * Wcl[1536 + h];
    float vr = a0 * Wcr[h] + a1 * Wcr[512 + h] + a2 * Wcr[1024 + h] + a3 * Wcr[1536 + h];
    Lw[(size_t)row * 1024 + h] = f2bf(vl);
    Rw[(size_t)row * 1024 + h] = f2bf(vr);
    float4 m4 = *(const float4*)(mm + (size_t)row * 2048 + h * 4);
    short4v o;
    o[0] = (short)f2bf(m4.x); o[1] = (short)f2bf(m4.y);
    o[2] = (short)f2bf(m4.z); o[3] = (short)f2bf(m4.w);
    *(short4v*)(mmb + (size_t)row * 2048 + h * 4) = o;
  } else {
    int gi = (bid - 2304) * 256 + threadIdx.x;  // 0..524287
    if (gi < 262144) {
      // WS granule gi = ((g2*32+kc)*4+q)*16+n ; elem e: d=g2*16+n, k=kc*32+q*8+e
      int n = gi & 15, qv = (gi >> 4) & 3, kc = (gi >> 6) & 31, g2 = gi >> 11;
      int d = g2 * 16 + n;
      int kbase = kc * 32 + qv * 8;
      const float* src = (kbase < 512) ? (Wcout + (size_t)kbase * 2048 + d)
                                       : (Wfout + (size_t)(kbase - 512) * 2048 + d);
      short8 o;
#pragma unroll
      for (int e = 0; e < 8; ++e) o[e] = (short)f2bf(src[(size_t)e * 2048]);
      *(short8*)(WS + (size_t)gi * 8) = o;
    } else {
      // WS2 granule gj = ((cg*64+kc)*4+q)*16+n ; elem e: col=cg*16+n, dd=kc*32+q*8+e
      int gj = gi - 262144;
      int n = gj & 15, qv = (gj >> 4) & 3, kc = (gj >> 6) & 63, cg = gj >> 12;
      int col = cg * 16 + n;
      int dbase = kc * 32 + qv * 8;
      const float* src = (col < 512) ? (Wfl + (size_t)dbase * 512 + col)
                                     : (Wfr + (size_t)dbase * 512 + (col - 512));
      short8 o;
#pragma unroll
      for (int e = 0; e < 8; ++e) o[e] = (short)f2bf(src[(size_t)e * 512]);
      *(short8*)(WS2 + (size_t)gj * 8) = o;
    }
  }
}

// ---------------------------------------------------------------------------
// K3: feature projection O[row,col] = sum_dd mmb[row,dd]*Wlr[dd,col]
//  col<512 -> fl -> Lw[row][512+col] ; else fr -> Rw[row][col]
__global__ __launch_bounds__(256) void k_proj_feat(
    const unsigned short* __restrict__ mmb, const unsigned short* __restrict__ WS2,
    unsigned short* __restrict__ Lw, unsigned short* __restrict__ Rw) {
  const int tid = threadIdx.x;
  const int lane = tid & 63, w = tid >> 6;
  const int n = lane & 15, q = lane >> 4;
  const int m0 = blockIdx.y * 16;
  const int cg = blockIdx.x * 4 + w;  // 0..63
  const int c0 = cg * 16;

  f32x4 acc = {0.f, 0.f, 0.f, 0.f};
#pragma unroll 4
  for (int kc = 0; kc < 64; ++kc) {
    short8 a = *(const short8*)(mmb + (size_t)(m0 + n) * 2048 + kc * 32 + q * 8);
    short8 b = *(const short8*)(WS2 + (size_t)(cg * 64 + kc) * 512 + lane * 8);
    acc = __builtin_amdgcn_mfma_f32_16x16x32_bf16(a, b, acc, 0, 0, 0);
  }
#pragma unroll
  for (int e = 0; e < 4; ++e) {
    int row = m0 + q * 4 + e;
    int col = c0 + n;
    unsigned short v = f2bf(acc[e]);
    if (col < 512) Lw[(size_t)row * 1024 + 512 + col] = v;
    else           Rw[(size_t)row * 1024 + col] = v;
  }
}

// ---------------------------------------------------------------------------
// K_prod: materialize pair products in MFMA B-fragment order, quad-packed.
// Quad-group qg (4 consecutive i's of one batch; 9 qg per batch, 288 total).
// Granule id = (qg*32 + kc)*9 + t ; lane (q,n), elem e: k = kc*32 + q*8 + e.
//   t<8 : group g = qg*4 + (t>>1), col j = (t&1)*16 + n      (full tiles)
//   t=8 : group g = qg*4 + (n>>2), col j = 32 + (n&3)        (shared remainder
//         tile: 4 groups x 4 j's = 16 cols, ZERO padding waste)
// P = clfl[g,k] * crfr[b,j,k], bf16. Writes perfectly coalesced (idx*16B).
__global__ __launch_bounds__(256) void k_prod(
    const unsigned short* __restrict__ Lw, const unsigned short* __restrict__ Rw,
    unsigned short* __restrict__ Pf) {
  int idx = blockIdx.x * 256 + threadIdx.x;  // 0 .. 5,308,415
  int lane = idx & 63;
  int gran = idx >> 6;          // 0 .. 82943
  int qg = gran / 288;          // 288 granules per quad-group (32 kc * 9 t)
  int rem = gran - qg * 288;
  int kc = rem / 9;
  int t = rem - kc * 9;
  int n = lane & 15, q = lane >> 4;
  int k0 = kc * 32 + q * 8;
  int b = qg / 9;
  int g, j;
  if (t < 8) { g = qg * 4 + (t >> 1); j = (t & 1) * 16 + n; }
  else       { g = qg * 4 + (n >> 2); j = 32 + (n & 3); }
  short8 cl8 = *(const short8*)(Lw + (size_t)g * 1024 + k0);
  short8 cr8 = *(const short8*)(Rw + (size_t)(b * 36 + j) * 1024 + k0);
  short8 p;
#pragma unroll
  for (int e = 0; e < 8; ++e)
    p[e] = (short)f2bf(bf2f((unsigned short)cl8[e]) * bf2f((unsigned short)cr8[e]));
  *(short8*)(Pf + (size_t)idx * 8) = p;
}

// ---------------------------------------------------------------------------
// K4: streaming GEMM + max-over-j + residual. Zero product VALU, zero padding.
// Block: 512 thr (8 waves), one quad-group x 256-d tile. grid 2304 = qg*8+dt
// (bx%8=dt -> per-XCD W-slice stays L2-resident). Per chunk (32 k): stage 9
// B-granules (9KB) via global_load_lds into dbuf LDS, 2 A-granules/wave from
// WS (reg dbuf), 18 MFMA/wave. acc 9 tiles x 2 r = 72 AGPR -> 2 waves/SIMD.
__global__ __launch_bounds__(512, 2) void k_pairwise(
    const unsigned short* __restrict__ Pf, const unsigned short* __restrict__ WS,
    const float* __restrict__ mm, float* __restrict__ out) {
  __shared__ __align__(16) unsigned short lB[2][9 * 512];  // 2 x 9 KB

  const int tid = threadIdx.x;
  const int lane = tid & 63, w = tid >> 6;  // w 0..7
  const int n = lane & 15, q = lane >> 4;
  const int bx = blockIdx.x;
  const int dt = bx & 7, qg = bx >> 3;  // dt 0..7, qg 0..287
  const int g0 = qg * 4;

  f32x4 acc[9][2];
#pragma unroll
  for (int t = 0; t < 9; ++t)
#pragma unroll
    for (int r = 0; r < 2; ++r) acc[t][r] = (f32x4){0.f, 0.f, 0.f, 0.f};

  // A granule (r, kc): WS + ((dt*16 + w*2 + r)*32 + kc)*512 + lane*8
  const unsigned short* Abase = WS + ((size_t)(dt * 16 + w * 2) * 32) * 512 + lane * 8;
  // B granule (kc, t): Pf + ((qg*32 + kc)*9 + t)*512 + lane*8
  const unsigned short* Bbase = Pf + (size_t)qg * 32 * 9 * 512;

  short8 aR[2], aN[2];
  // prologue: stage kc=0, load A(kc=0)
  gl2lds16(Bbase + (size_t)w * 512 + lane * 8, &lB[0][w * 512]);
  if (w == 0) gl2lds16(Bbase + (size_t)8 * 512 + lane * 8, &lB[0][8 * 512]);
  aR[0] = *(const short8*)(Abase);
  aR[1] = *(const short8*)(Abase + 32 * 512);
  __syncthreads();  // vmcnt(0) drain before barrier -> lB[0] ready

#pragma unroll 2
  for (int kc = 0; kc < 32; ++kc) {
    const int buf = kc & 1;
    if (kc < 31) {
      const unsigned short* bn = Bbase + (size_t)((kc + 1) * 9) * 512 + lane * 8;
      gl2lds16(bn + (size_t)w * 512, &lB[buf ^ 1][w * 512]);
      if (w == 0) gl2lds16(bn + (size_t)8 * 512, &lB[buf ^ 1][8 * 512]);
      aN[0] = *(const short8*)(Abase + (size_t)(kc + 1) * 512);
      aN[1] = *(const short8*)(Abase + (size_t)(32 + kc + 1) * 512);
    }
    short8 bb[9];
#pragma unroll
    for (int t = 0; t < 9; ++t)
      bb[t] = *(const short8*)(&lB[buf][t * 512 + lane * 8]);
#pragma unroll
    for (int t = 0; t < 9; ++t) {
      acc[t][0] = __builtin_amdgcn_mfma_f32_16x16x32_bf16(aR[0], bb[t], acc[t][0], 0, 0, 0);
      acc[t][1] = __builtin_amdgcn_mfma_f32_16x16x32_bf16(aR[1], bb[t], acc[t][1], 0, 0, 0);
    }
    __syncthreads();  // all waves done reading buf; staged buf^1 complete
    aR[0] = aN[0];
    aR[1] = aN[1];
  }

  // epilogue: per (ii,r,e): max over full tiles 2ii,2ii+1 (j=n, 16+n) and the
  // shared tile's lanes with n>>2==ii (j=32+(n&3)); xor-reduce over 16 n-lanes.
#pragma unroll
  for (int r = 0; r < 2; ++r) {
#pragma unroll
    for (int e = 0; e < 4; ++e) {
      float vs = acc[8][r][e];
#pragma unroll
      for (int ii = 0; ii < 4; ++ii) {
        float v = fmaxf(acc[ii * 2][r][e], acc[ii * 2 + 1][r][e]);
        v = fmaxf(v, ((n >> 2) == ii) ? vs : -1e30f);
#pragma unroll
        for (int s = 1; s < 16; s <<= 1) v = fmaxf(v, __shfl_xor(v, s, 64));
        if (n == 0) {
          int d = dt * 256 + w * 32 + r * 16 + q * 4 + e;
          size_t o = (size_t)(g0 + ii) * 2048 + d;
          out[o] = v + mm[o];
        }
      }
    }
  }
}

// ---------------------------------------------------------------------------
extern "C" void kernel_launch(void* const* d_in, const int* in_sizes, int n_in,
                              void* d_out, int out_size, void* d_ws, size_t ws_size,
                              hipStream_t stream) {
  const float* mm     = (const float*)d_in[0];
  const float* coords = (const float*)d_in[1];
  const float* Wcl    = (const float*)d_in[2];
  const float* Wcr    = (const float*)d_in[3];
  const float* Wcout  = (const float*)d_in[4];
  const float* Wfl    = (const float*)d_in[5];
  const float* Wfr    = (const float*)d_in[6];
  const float* Wfout  = (const float*)d_in[7];
  float* out = (float*)d_out;

  // workspace (bf16 shorts), ~103 MB total
  unsigned short* Lw  = (unsigned short*)d_ws;   // [1152][1024]  cl | fl
  unsigned short* Rw  = Lw + 1152 * 1024;        // [1152][1024]  cr | fr
  unsigned short* WS  = Rw + 1152 * 1024;        // 262144 granules x 8 (Wcat^T frag)
  unsigned short* WS2 = WS + (size_t)262144 * 8; // 262144 granules x 8 ((Wfl|Wfr)^T frag)
  unsigned short* mmb = WS2 + (size_t)262144 * 8;// [1152][2048]  mm in bf16
  unsigned short* Pf  = mmb + (size_t)1152 * 2048; // 82944 granules x 512 (products, 85MB)

  k_prep<<<2304 + 2048, 256, 0, stream>>>(coords, Wcl, Wcr, mm, Wcout, Wfout,
                                          Wfl, Wfr, Lw, Rw, mmb, WS, WS2);
  k_proj_feat<<<dim3(16, 72), 256, 0, stream>>>(mmb, WS2, Lw, Rw);
  k_prod<<<20736, 256, 0, stream>>>(Lw, Rw, Pf);
  k_pairwise<<<2304, 512, 0, stream>>>(Pf, WS, mm, out);
}